// Round 3
// baseline (517.676 us; speedup 1.0000x reference)
//
#include <hip/hip_runtime.h>
#include <math.h>

// Problem constants: B=512, N=600, H=256, K=9, WIN=129
#define BB   512
#define NN   600
#define HH   256
#define KS   9
#define WIN  129
#define PADW 4
#define PWIN 137           // WIN + 2*PAD
#define NP   608           // N + 2*PAD

// One block per batch, 1024 threads (16 waves).
// KEY CHANGE vs prior rounds: the tokens window (Phase C input, 132 KB/block)
// is prefetched into REGISTERS at kernel entry (8 float4/thread + wave-0 tail),
// merging the kernel's two HBM bursts (token_keys in Phase B, tokens in Phase C)
// into one overlapped burst. Phase C after softmax is pure register math.
// Occupancy experiments (R0: 16w/1blk, R2: 8w/4blk) were neutral -> kernel is
// not latency-bound; this attacks the serial burst chain instead.
__global__ __launch_bounds__(1024) void attn_kernel(
    const float* __restrict__ tokens,       // (B,N,H)
    const float* __restrict__ token_keys,   // (B,H,N)
    const int*   __restrict__ num_tokens,   // (B,)
    const float* __restrict__ query,        // (B,H)
    const float* __restrict__ alignment,    // (B,NP)
    const float* __restrict__ cum_align,    // (B,NP)
    const int*   __restrict__ window_start, // (B,)
    const float* __restrict__ conv_w,       // (H,2,K)
    const float* __restrict__ conv_b,       // (H,)
    float* __restrict__ out)
{
  const int b    = blockIdx.x;
  const int t    = threadIdx.x;
  const int lane = t & 63;
  const int wv   = t >> 6;            // 0..15

  __shared__ float sq[HH];            // query row (1 KB)
  __shared__ float p0[PWIN], p1[PWIN];
  __shared__ float cred[19][8];       // conv-fold partials
  __shared__ float w128red[4];        // w=128 column dot partials
  __shared__ float sqc[19];           // folded conv scalars
  __shared__ float sS[8][130];        // per-h-group score partials
  __shared__ float salign[WIN];       // raw scores, then e-values
  __shared__ __align__(16) float sctx[16][HH]; // context partials (16 KB)
  __shared__ float s_sum;
  __shared__ int   s_arg;

  const int ws = window_start[b];
  const int nt = num_tokens[b];
  const float* __restrict__ Kb = token_keys + (size_t)b * (HH * NN);
  const float* __restrict__ Tb = tokens + (size_t)b * (NN * HH) + (size_t)ws * HH;

  // ---- Token-window prefetch: issue ALL Phase-C loads up front ----
  // thread (wv, lane) owns rows w = wv + 16*i (i=0..7), float4-column = lane.
  // These sit in VGPRs across Phase B + softmax; consumed register-only later.
  float4 r0, r1, r2, r3, r4, r5, r6, r7;
  {
    const float4* T4 = (const float4*)Tb;
    r0 = T4[(size_t)(wv +   0) * 64 + lane];
    r1 = T4[(size_t)(wv +  16) * 64 + lane];
    r2 = T4[(size_t)(wv +  32) * 64 + lane];
    r3 = T4[(size_t)(wv +  48) * 64 + lane];
    r4 = T4[(size_t)(wv +  64) * 64 + lane];
    r5 = T4[(size_t)(wv +  80) * 64 + lane];
    r6 = T4[(size_t)(wv +  96) * 64 + lane];
    r7 = T4[(size_t)(wv + 112) * 64 + lane];
  }
  float4 r8 = make_float4(0.f, 0.f, 0.f, 0.f);
  if (wv == 0) r8 = ((const float4*)Tb)[(size_t)128 * 64 + lane];

  // Prefetch cum_align value needed by the out3 epilogue
  const float cum0 = (t < NP) ? cum_align[b * NP + t] : 0.f;

  // ---- Stage small inputs to LDS ----
  float qreg = 0.f;
  if (t < HH) { qreg = query[b * HH + t]; sq[t] = qreg; }
  if (t < PWIN) {
    p0[t] = cum_align[b * NP + ws + t] * (1.0f / 1.5f) - 1.0f;
    p1[t] = alignment[b * NP + ws + t] * 2.0f - 1.0f;
  }
  __syncthreads();

  // ---- Phase B: keys dot. wave wv: h-group hh=wv&7 (32 rows), col w=(wv>>3)*64+lane ----
  {
    const int hh   = wv & 7;
    const int wseg = wv >> 3;
    const int w    = wseg * 64 + lane;     // 0..127
    const float* __restrict__ Kp  = Kb + (size_t)(hh * 32) * NN + ws + w;
    const float* __restrict__ sqp = sq + hh * 32;
    float acc = 0.f;
    #pragma unroll 8
    for (int h = 0; h < 32; ++h) acc += sqp[h] * Kp[(size_t)h * NN];
    sS[hh][w] = acc;
  }

  // ---- w=128 column dot (threads 0..255, thread t owns h=t) ----
  if (t < HH) {
    float v = qreg * Kb[(size_t)t * NN + ws + 128];
    #pragma unroll
    for (int off = 32; off; off >>= 1) v += __shfl_xor(v, off, 64);
    if (lane == 0) w128red[wv] = v;
  }

  // ---- Conv fold (conv_w/conv_b straight from global: L2-resident) ----
  if (t < 152) {
    const int j = t >> 3, seg = t & 7;
    const int h0 = seg * 32;
    float a = 0.f;
    if (j < 18) {
      #pragma unroll 4
      for (int h = 0; h < 32; ++h) a += sq[h0 + h] * conv_w[(h0 + h) * 18 + j];
    } else {
      #pragma unroll 4
      for (int h = 0; h < 32; ++h) a += sq[h0 + h] * conv_b[h0 + h];
    }
    cred[j][seg] = a;
  }
  __syncthreads();

  if (t < 19) {
    const float* c = cred[t];
    sqc[t] = ((c[0] + c[1]) + (c[2] + c[3])) + ((c[4] + c[5]) + (c[6] + c[7]));
  }
  __syncthreads();

  // ---- Score assembly (threads 0..128) -> raw scores in salign ----
  if (t < WIN) {
    float dot;
    if (t < 128) {
      dot = 0.f;
      #pragma unroll
      for (int g = 0; g < 8; ++g) dot += sS[g][t];
    } else {
      dot = w128red[0] + w128red[1] + w128red[2] + w128red[3];
    }
    float f = sqc[18];
    #pragma unroll
    for (int k = 0; k < KS; ++k) f += sqc[k] * p0[t + k] + sqc[9 + k] * p1[t + k];
    float sc = (dot + f) * 0.0625f;               // / sqrt(256)
    if (ws + t >= nt) sc = -INFINITY;
    salign[t] = sc;
  }
  __syncthreads();

  // ---- Fused softmax: max + argmax + exp + sum entirely inside wave 0 ----
  if (t < 64) {
    const float a0 = salign[t];
    const float a1 = salign[t + 64];
    const float a2 = (t == 0) ? salign[128] : -INFINITY;
    float m = a0; int idx = t;                    // first-index tie semantics
    if (a1 > m) { m = a1; idx = t + 64; }
    if (a2 > m) { m = a2; idx = 128; }
    #pragma unroll
    for (int off = 32; off; off >>= 1) {
      const float om = __shfl_xor(m, off, 64);
      const int   oi = __shfl_xor(idx, off, 64);
      if (om > m || (om == m && oi < idx)) { m = om; idx = oi; }
    }
    const float e0 = expf(a0 - m);
    const float e1 = expf(a1 - m);
    salign[t]      = e0;
    salign[t + 64] = e1;
    float s = e0 + e1;
    if (t == 0) { const float e2 = expf(a2 - m); salign[128] = e2; s += e2; }
    #pragma unroll
    for (int off = 32; off; off >>= 1) s += __shfl_xor(s, off, 64);
    if (t == 0) { s_sum = s; s_arg = idx; }
  }
  __syncthreads();

  const float inv = 1.0f / s_sum;                 // normalization folded into writes

  // ---- Output pointers ----
  float* out0 = out;                       // context     (B,H)
  float* out1 = out0 + BB * HH;            // unpadded    (B,N)
  float* out2 = out1 + BB * NN;            // full_align  (B,NP)
  float* out3 = out2 + BB * NP;            // cum+align   (B,NP)
  float* out4 = out3 + BB * NP;            // new_start   (B,) as float

  // ---- Phase C: context from PREFETCHED registers (no global loads) ----
  {
    float4 acc;
    float a;
    a = salign[wv +   0]; acc.x  = a * r0.x; acc.y  = a * r0.y; acc.z  = a * r0.z; acc.w  = a * r0.w;
    a = salign[wv +  16]; acc.x += a * r1.x; acc.y += a * r1.y; acc.z += a * r1.z; acc.w += a * r1.w;
    a = salign[wv +  32]; acc.x += a * r2.x; acc.y += a * r2.y; acc.z += a * r2.z; acc.w += a * r2.w;
    a = salign[wv +  48]; acc.x += a * r3.x; acc.y += a * r3.y; acc.z += a * r3.z; acc.w += a * r3.w;
    a = salign[wv +  64]; acc.x += a * r4.x; acc.y += a * r4.y; acc.z += a * r4.z; acc.w += a * r4.w;
    a = salign[wv +  80]; acc.x += a * r5.x; acc.y += a * r5.y; acc.z += a * r5.z; acc.w += a * r5.w;
    a = salign[wv +  96]; acc.x += a * r6.x; acc.y += a * r6.y; acc.z += a * r6.z; acc.w += a * r6.w;
    a = salign[wv + 112]; acc.x += a * r7.x; acc.y += a * r7.y; acc.z += a * r7.z; acc.w += a * r7.w;
    if (wv == 0) {
      a = salign[128];    acc.x += a * r8.x; acc.y += a * r8.y; acc.z += a * r8.z; acc.w += a * r8.w;
    }
    ((float4*)&sctx[wv][0])[lane] = acc;
  }

  // ---- Scatter outputs (independent of sctx; overlaps other waves' Phase C) ----
  if (t < NN) {
    const float v = (t >= ws && t <= ws + 128) ? salign[t - ws] * inv : 0.f;
    out1[b * NN + t] = v;
  }
  if (t < NP) {
    const float v = (t >= ws + PADW && t <= ws + PADW + 128) ? salign[t - ws - PADW] * inv : 0.f;
    out2[b * NP + t] = v;
    out3[b * NP + t] = v + cum0;
  }
  if (t == 0) {
    int jstar = ws + PADW + s_arg;
    int ns = jstar - (PWIN / 2);
    ns = max(ws, ns);
    ns = min(ns, nt - WIN);
    ns = max(ns, 0);
    out4[b] = (float)ns;
  }
  __syncthreads();

  // ---- Context final reduce + write ----
  if (t < HH) {
    float c = 0.f;
    #pragma unroll
    for (int v = 0; v < 16; ++v) c += sctx[v][t];
    out0[b * HH + t] = c * inv;
  }
}

extern "C" void kernel_launch(void* const* d_in, const int* in_sizes, int n_in,
                              void* d_out, int out_size, void* d_ws, size_t ws_size,
                              hipStream_t stream) {
  const float* tokens       = (const float*)d_in[0];
  // d_in[1] = tokens_mask (bool) — recomputed from num_tokens, unused
  const float* token_keys   = (const float*)d_in[2];
  const int*   num_tokens   = (const int*)d_in[3];
  const float* query        = (const float*)d_in[4];
  const float* alignment    = (const float*)d_in[5];
  const float* cum_align    = (const float*)d_in[6];
  const int*   window_start = (const int*)d_in[7];
  const float* conv_w       = (const float*)d_in[8];
  const float* conv_b       = (const float*)d_in[9];

  attn_kernel<<<BB, 1024, 0, stream>>>(tokens, token_keys, num_tokens, query,
                                       alignment, cum_align, window_start,
                                       conv_w, conv_b, (float*)d_out);
}